// Round 9
// baseline (683.275 us; speedup 1.0000x reference)
//
#include <hip/hip_runtime.h>
#include <math.h>

#define H 1024
#define NHEAD 16
#define HDIM 64
#define IDIM 4096
#define BATCH 4
#define SEQ 2048
#define NTOK 8192
#define LN_EPS 1e-5f

// 0.125 * log2(e): folded into Q at QKV-GEMM epilogue so attention's softmax
// is a raw v_exp_f32 (2^x) with zero preceding VALU muls.
#define QK_EXP2_SCALE 0.18033688011112042f

typedef __bf16 bf16x8 __attribute__((ext_vector_type(8)));
typedef __bf16 bf16x4 __attribute__((ext_vector_type(4)));
typedef float f32x4 __attribute__((ext_vector_type(4)));
typedef unsigned short ushort8 __attribute__((ext_vector_type(8)));
typedef unsigned short ushort4v __attribute__((ext_vector_type(4)));

__device__ __forceinline__ unsigned short f2bf(float f) {
  union { float f; unsigned int u; } v; v.f = f;
  unsigned int u = v.u;
  return (unsigned short)((u + 0x7FFFu + ((u >> 16) & 1u)) >> 16);
}

// ---------- fused transpose + cast: 4 weight matrices in ONE launch ----------
__global__ void transpose_cast_all(const float* __restrict__ W0, unsigned short* __restrict__ T0,
                                   const float* __restrict__ W1, unsigned short* __restrict__ T1,
                                   const float* __restrict__ W2, unsigned short* __restrict__ T2,
                                   const float* __restrict__ W3, unsigned short* __restrict__ T3) {
  __shared__ unsigned short tile[32][33];
  int bid = blockIdx.x;
  const float* W;
  unsigned short* Wt;
  int K, N, ntx, local;
  if (bid < 3072) {
    W = W0; Wt = T0; K = H; N = 3 * H; ntx = 3 * H / 32; local = bid;
  } else if (bid < 4096) {
    W = W1; Wt = T1; K = H; N = H; ntx = H / 32; local = bid - 3072;
  } else if (bid < 8192) {
    W = W2; Wt = T2; K = H; N = IDIM; ntx = IDIM / 32; local = bid - 4096;
  } else {
    W = W3; Wt = T3; K = IDIM; N = H; ntx = H / 32; local = bid - 8192;
  }
  int n0 = (local % ntx) * 32, k0 = (local / ntx) * 32;
  int tx = threadIdx.x, ty = threadIdx.y;  // 32 x 8
#pragma unroll
  for (int i = 0; i < 4; i++) {
    int k = ty + i * 8;
    tile[tx][k] = f2bf(W[(size_t)(k0 + k) * N + n0 + tx]);
  }
  __syncthreads();
#pragma unroll
  for (int i = 0; i < 4; i++) {
    int n = ty + i * 8;
    Wt[(size_t)(n0 + n) * K + k0 + tx] = tile[n][tx];
  }
}

// ---------- layernorm: f32 [rows][H] -> bf16 ----------
__global__ __launch_bounds__(256)
void layernorm_kernel(const float* __restrict__ x, const float* __restrict__ g,
                      const float* __restrict__ b, unsigned short* __restrict__ out) {
  __shared__ float sb[4];
  int row = blockIdx.x;
  int tid = threadIdx.x;
  const float4* xr = (const float4*)(x + (size_t)row * H);
  float4 v = xr[tid];
  float s = v.x + v.y + v.z + v.w;
#pragma unroll
  for (int o = 32; o > 0; o >>= 1) s += __shfl_down(s, o);
  if ((tid & 63) == 0) sb[tid >> 6] = s;
  __syncthreads();
  float mu = (sb[0] + sb[1] + sb[2] + sb[3]) * (1.0f / H);
  __syncthreads();
  float dx = v.x - mu, dy = v.y - mu, dz = v.z - mu, dw = v.w - mu;
  float s2 = dx * dx + dy * dy + dz * dz + dw * dw;
#pragma unroll
  for (int o = 32; o > 0; o >>= 1) s2 += __shfl_down(s2, o);
  if ((tid & 63) == 0) sb[tid >> 6] = s2;
  __syncthreads();
  float var = (sb[0] + sb[1] + sb[2] + sb[3]) * (1.0f / H);
  float rs = rsqrtf(var + LN_EPS);
  float4 gv = ((const float4*)g)[tid];
  float4 bv = ((const float4*)b)[tid];
  ushort4v ov;
  ov[0] = f2bf(dx * rs * gv.x + bv.x);
  ov[1] = f2bf(dy * rs * gv.y + bv.y);
  ov[2] = f2bf(dz * rs * gv.z + bv.z);
  ov[3] = f2bf(dw * rs * gv.w + bv.w);
  ((ushort4v*)(out + (size_t)row * H))[tid] = ov;
}

// ---------- GEMM 128^2 (proven single-barrier structure) ----------
// proj + MLP2 fallback. m-grouped XCD swizzle: XCD k takes m-tiles [8k,8k+8)
// x all n, so its A panel (2MB) + B (2MB) fit one 4MB L2 (R8, validated).
template <int EPI>
__global__ __launch_bounds__(256)
void gemm_bt_kernel(const unsigned short* __restrict__ A,
                    const unsigned short* __restrict__ Bt,
                    const float* __restrict__ bias,
                    const float* __restrict__ res,
                    void* __restrict__ out, unsigned short* __restrict__ vt_out,
                    int M, int N, int K) {
  __shared__ __align__(16) unsigned short As[2][128 * 32];
  __shared__ __align__(16) unsigned short Bs[2][128 * 32];
  int tid = threadIdx.x;
  int wave = tid >> 6, lane = tid & 63;
  int quad = lane >> 4, l16 = lane & 15;
  int wm = wave >> 1, wn = wave & 1;
  int nwg = gridDim.x * gridDim.y;
  int dlin = blockIdx.y * gridDim.x + blockIdx.x;
  int swz = (nwg & 7) ? dlin : ((dlin & 7) * (nwg >> 3) + (dlin >> 3));
  int mt = swz / gridDim.x, nt = swz % gridDim.x;  // m-major decode
  int m0 = mt * 128, n0 = nt * 128;
  f32x4 acc[4][4];
#pragma unroll
  for (int i = 0; i < 4; i++)
#pragma unroll
    for (int j = 0; j < 4; j++) acc[i][j] = (f32x4){0.f, 0.f, 0.f, 0.f};

  int rl = (lane >> 2);
  int cphys = lane & 3;

  auto stage = [&](int k0, int sel) {
#pragma unroll
    for (int t = 0; t < 2; t++) {
      int ch = wave * 2 + t;
      int rloc = ch * 16 + rl;
      int clog = cphys ^ ((rloc >> 1) & 3);
      const unsigned short* ga = A + (size_t)(m0 + rloc) * K + k0 + clog * 8;
      __builtin_amdgcn_global_load_lds(
          (const __attribute__((address_space(1))) unsigned int*)ga,
          (__attribute__((address_space(3))) unsigned int*)(&As[sel][ch * 512]), 16, 0, 0);
      const unsigned short* gb = Bt + (size_t)(n0 + rloc) * K + k0 + clog * 8;
      __builtin_amdgcn_global_load_lds(
          (const __attribute__((address_space(1))) unsigned int*)gb,
          (__attribute__((address_space(3))) unsigned int*)(&Bs[sel][ch * 512]), 16, 0, 0);
    }
  };

  stage(0, 0);
  for (int k0 = 0; k0 < K; k0 += 32) {
    int sel = (k0 >> 5) & 1;
    __syncthreads();
    if (k0 + 32 < K) stage(k0 + 32, sel ^ 1);
    bf16x8 af[4], bfv[4];
#pragma unroll
    for (int i = 0; i < 4; i++) {
      int ra = wm * 64 + i * 16 + l16;
      af[i] = *(const bf16x8*)&As[sel][ra * 32 + ((quad ^ ((ra >> 1) & 3)) << 3)];
      int rb = wn * 64 + i * 16 + l16;
      bfv[i] = *(const bf16x8*)&Bs[sel][rb * 32 + ((quad ^ ((rb >> 1) & 3)) << 3)];
    }
#pragma unroll
    for (int i = 0; i < 4; i++)
#pragma unroll
      for (int j = 0; j < 4; j++)
        acc[i][j] = __builtin_amdgcn_mfma_f32_16x16x32_bf16(bfv[j], af[i], acc[i][j], 0, 0, 0);
  }
#pragma unroll
  for (int i = 0; i < 4; i++) {
    int m = m0 + wm * 64 + i * 16 + l16;
#pragma unroll
    for (int j = 0; j < 4; j++) {
      int nb = n0 + wn * 64 + j * 16 + quad * 4;
      float4 bv4 = *(const float4*)&bias[nb];
      float v0 = acc[i][j][0] + bv4.x;
      float v1 = acc[i][j][1] + bv4.y;
      float v2 = acc[i][j][2] + bv4.z;
      float v3 = acc[i][j][3] + bv4.w;
      size_t off = (size_t)m * N + nb;
      float4 rv = *(const float4*)&res[off];
      float4 o4;
      o4.x = v0 + rv.x; o4.y = v1 + rv.y; o4.z = v2 + rv.z; o4.w = v3 + rv.w;
      *(float4*)&((float*)out)[off] = o4;
    }
  }
}

// ---------- GEMM 256^2 8-phase (race-fixed ledger, see R5 notes) ----------
// QKV + MLP1. Stages issue only after their region's last read; vmcnt(6)@P3
// lands tile t+1, vmcnt(8)@P7 lands tile t+2.
template <int EPI>
__global__ __launch_bounds__(512, 2)
void gemm256_kernel(const unsigned short* __restrict__ A,
                    const unsigned short* __restrict__ Bt,
                    const float* __restrict__ bias,
                    void* __restrict__ out, unsigned short* __restrict__ vt_out,
                    int M, int N, int K) {
  __shared__ __align__(16) unsigned short As[2][256 * 64];
  __shared__ __align__(16) unsigned short Bs[2][256 * 64];
  int tid = threadIdx.x;
  int wave = tid >> 6, lane = tid & 63;
  int quad = lane >> 4, l16 = lane & 15;
  int wm = wave >> 2, wn = wave & 3;
  int nwg = gridDim.x * gridDim.y;
  int dlin = blockIdx.y * gridDim.x + blockIdx.x;
  int swz = (dlin & 7) * (nwg >> 3) + (dlin >> 3);
  int nm = gridDim.y;  // M/256
  int mt = swz % nm, nt = swz / nm;
  int m0 = mt * 256, n0 = nt * 256;
  int NT = K >> 6;

  const unsigned short* Abase = A + (size_t)m0 * K;
  const unsigned short* Bbase = Bt + (size_t)n0 * K;

  int srow = lane >> 3;
  int schunk = (lane & 7) ^ srow;

  auto stage = [&](const unsigned short* gbase, unsigned short* lbase, int tile,
                   int half) {
    int kt = tile < NT ? tile : NT - 1;
    int k0 = kt << 6;
    unsigned short* lb = lbase + (size_t)(tile & 1) * (256 * 64);
#pragma unroll
    for (int L = 0; L < 2; L++) {
      int rloc = half * 128 + L * 64 + wave * 8 + srow;
      const unsigned short* g = gbase + (size_t)rloc * K + k0 + schunk * 8;
      __builtin_amdgcn_global_load_lds(
          (const __attribute__((address_space(1))) unsigned int*)g,
          (__attribute__((address_space(3))) unsigned int*)(lb + (size_t)(half * 128 + L * 64 + wave * 8) * 64),
          16, 0, 0);
    }
  };

  f32x4 acc[8][4];
#pragma unroll
  for (int i = 0; i < 8; i++)
#pragma unroll
    for (int j = 0; j < 4; j++) acc[i][j] = (f32x4){0.f, 0.f, 0.f, 0.f};
  bf16x8 af[4][2];
  bf16x8 bv[4][2];

  stage(Abase, (unsigned short*)As, 0, 0);
  stage(Bbase, (unsigned short*)Bs, 0, 0);
  stage(Abase, (unsigned short*)As, 0, 1);
  stage(Bbase, (unsigned short*)Bs, 0, 1);
  stage(Abase, (unsigned short*)As, 1, 0);
  stage(Bbase, (unsigned short*)Bs, 1, 0);
  stage(Abase, (unsigned short*)As, 1, 1);
  stage(Bbase, (unsigned short*)Bs, 1, 1);
  asm volatile("s_waitcnt vmcnt(8)" ::: "memory");
  __builtin_amdgcn_s_barrier();

  for (int it = 0; it < (NT >> 1); it++) {
    int t = it * 2;
#pragma unroll
    for (int P = 0; P < 8; P++) {
      int ct = t + (P >> 2);
      int sel = ct & 1;
      if ((P & 3) == 0) {
#pragma unroll
        for (int i = 0; i < 4; i++) {
          int ra = wm * 128 + i * 16 + l16;
#pragma unroll
          for (int ks = 0; ks < 2; ks++)
            af[i][ks] = *(const bf16x8*)&As[sel][ra * 64 + (((ks * 4 + quad) ^ (ra & 7)) << 3)];
        }
#pragma unroll
        for (int j = 0; j < 2; j++) {
          int rb = wn * 64 + j * 16 + l16;
#pragma unroll
          for (int ks = 0; ks < 2; ks++)
            bv[j][ks] = *(const bf16x8*)&Bs[sel][rb * 64 + (((ks * 4 + quad) ^ (rb & 7)) << 3)];
        }
      } else if ((P & 3) == 1) {
#pragma unroll
        for (int j = 0; j < 2; j++) {
          int rb = wn * 64 + (2 + j) * 16 + l16;
#pragma unroll
          for (int ks = 0; ks < 2; ks++)
            bv[2 + j][ks] = *(const bf16x8*)&Bs[sel][rb * 64 + (((ks * 4 + quad) ^ (rb & 7)) << 3)];
        }
      } else if ((P & 3) == 2) {
#pragma unroll
        for (int i = 0; i < 4; i++) {
          int ra = wm * 128 + (4 + i) * 16 + l16;
#pragma unroll
          for (int ks = 0; ks < 2; ks++)
            af[i][ks] = *(const bf16x8*)&As[sel][ra * 64 + (((ks * 4 + quad) ^ (ra & 7)) << 3)];
        }
      }
      switch (P) {
        case 2: stage(Bbase, (unsigned short*)Bs, t + 2, 0); break;
        case 3: stage(Abase, (unsigned short*)As, t + 2, 0);
                stage(Bbase, (unsigned short*)Bs, t + 2, 1); break;
        case 4: stage(Abase, (unsigned short*)As, t + 2, 1); break;
        case 6: stage(Bbase, (unsigned short*)Bs, t + 3, 0);
                stage(Bbase, (unsigned short*)Bs, t + 3, 1); break;
        case 7: stage(Abase, (unsigned short*)As, t + 3, 0);
                stage(Abase, (unsigned short*)As, t + 3, 1); break;
        default: break;
      }
      __builtin_amdgcn_s_barrier();
      int qm = (P >> 1) & 1, qj = P & 1;
      __builtin_amdgcn_s_setprio(1);
#pragma unroll
      for (int i = 0; i < 4; i++)
#pragma unroll
        for (int j = 0; j < 2; j++)
#pragma unroll
          for (int ks = 0; ks < 2; ks++)
            acc[qm * 4 + i][qj * 2 + j] = __builtin_amdgcn_mfma_f32_16x16x32_bf16(
                bv[qj * 2 + j][ks], af[i][ks], acc[qm * 4 + i][qj * 2 + j], 0, 0, 0);
      __builtin_amdgcn_s_setprio(0);
      if (P == 3) asm volatile("s_waitcnt vmcnt(6)" ::: "memory");
      if (P == 7) asm volatile("s_waitcnt vmcnt(8)" ::: "memory");
      __builtin_amdgcn_s_barrier();
    }
  }
  asm volatile("s_waitcnt vmcnt(0)" ::: "memory");

  bool vslice = (EPI == 0) && (vt_out != nullptr) && (n0 >= 2 * H);
#pragma unroll
  for (int i = 0; i < 8; i++) {
    int m = m0 + wm * 128 + i * 16 + l16;
#pragma unroll
    for (int j = 0; j < 4; j++) {
      int nb = n0 + wn * 64 + j * 16 + quad * 4;
      float4 bv4 = *(const float4*)&bias[nb];
      float v0 = acc[i][j][0] + bv4.x;
      float v1 = acc[i][j][1] + bv4.y;
      float v2 = acc[i][j][2] + bv4.z;
      float v3 = acc[i][j][3] + bv4.w;
      size_t off = (size_t)m * N + nb;
      if (EPI == 0) {
        if (vslice) {
          int bb = m >> 11, s = m & (SEQ - 1);
          int cb = nb - 2 * H;
          int hh = cb >> 6, dd = cb & 63;
          size_t base = ((size_t)(bb * NHEAD + hh) * HDIM + dd) * SEQ + s;
          vt_out[base] = f2bf(v0);
          vt_out[base + SEQ] = f2bf(v1);
          vt_out[base + 2 * SEQ] = f2bf(v2);
          vt_out[base + 3 * SEQ] = f2bf(v3);
        } else {
          if (n0 < H) {
            v0 *= QK_EXP2_SCALE; v1 *= QK_EXP2_SCALE;
            v2 *= QK_EXP2_SCALE; v3 *= QK_EXP2_SCALE;
          }
          bf16x4 pk = {(__bf16)v0, (__bf16)v1, (__bf16)v2, (__bf16)v3};
          *(bf16x4*)&((unsigned short*)out)[off] = pk;
        }
      } else {
        float g0 = v0 / (1.f + __expf(-1.5957691216057308f * (v0 + 0.044715f * v0 * v0 * v0)));
        float g1 = v1 / (1.f + __expf(-1.5957691216057308f * (v1 + 0.044715f * v1 * v1 * v1)));
        float g2 = v2 / (1.f + __expf(-1.5957691216057308f * (v2 + 0.044715f * v2 * v2 * v2)));
        float g3 = v3 / (1.f + __expf(-1.5957691216057308f * (v3 + 0.044715f * v3 * v3 * v3)));
        bf16x4 pk = {(__bf16)g0, (__bf16)g1, (__bf16)g2, (__bf16)g3};
        *(bf16x4*)&((unsigned short*)out)[off] = pk;
      }
    }
  }
}

// ---------- GEMM 256^2 split-K=2 (MLP2): f32 partials (R8, validated) ----------
__global__ __launch_bounds__(512, 2)
void gemm256_sk_kernel(const unsigned short* __restrict__ A,
                       const unsigned short* __restrict__ Bt,
                       float* __restrict__ opart,
                       int M, int N, int Kf, int KL) {
  __shared__ __align__(16) unsigned short As[2][256 * 64];
  __shared__ __align__(16) unsigned short Bs[2][256 * 64];
  int tid = threadIdx.x;
  int wave = tid >> 6, lane = tid & 63;
  int quad = lane >> 4, l16 = lane & 15;
  int wm = wave >> 2, wn = wave & 3;
  int d = blockIdx.x;
  int swz = (d & 7) * 32 + (d >> 3);
  int sp = swz >> 7;
  int rem = swz & 127;
  int mt = rem >> 2, nt = rem & 3;
  int m0 = mt * 256, n0 = nt * 256;
  int NT = KL >> 6;
  int k0g = sp * KL;

  const unsigned short* Abase = A + (size_t)m0 * Kf + k0g;
  const unsigned short* Bbase = Bt + (size_t)n0 * Kf + k0g;

  int srow = lane >> 3;
  int schunk = (lane & 7) ^ srow;

  auto stage = [&](const unsigned short* gbase, unsigned short* lbase, int tile,
                   int half) {
    int kt = tile < NT ? tile : NT - 1;
    int k0 = kt << 6;
    unsigned short* lb = lbase + (size_t)(tile & 1) * (256 * 64);
#pragma unroll
    for (int L = 0; L < 2; L++) {
      int rloc = half * 128 + L * 64 + wave * 8 + srow;
      const unsigned short* g = gbase + (size_t)rloc * Kf + k0 + schunk * 8;
      __builtin_amdgcn_global_load_lds(
          (const __attribute__((address_space(1))) unsigned int*)g,
          (__attribute__((address_space(3))) unsigned int*)(lb + (size_t)(half * 128 + L * 64 + wave * 8) * 64),
          16, 0, 0);
    }
  };

  f32x4 acc[8][4];
#pragma unroll
  for (int i = 0; i < 8; i++)
#pragma unroll
    for (int j = 0; j < 4; j++) acc[i][j] = (f32x4){0.f, 0.f, 0.f, 0.f};
  bf16x8 af[4][2];
  bf16x8 bv[4][2];

  stage(Abase, (unsigned short*)As, 0, 0);
  stage(Bbase, (unsigned short*)Bs, 0, 0);
  stage(Abase, (unsigned short*)As, 0, 1);
  stage(Bbase, (unsigned short*)Bs, 0, 1);
  stage(Abase, (unsigned short*)As, 1, 0);
  stage(Bbase, (unsigned short*)Bs, 1, 0);
  stage(Abase, (unsigned short*)As, 1, 1);
  stage(Bbase, (unsigned short*)Bs, 1, 1);
  asm volatile("s_waitcnt vmcnt(8)" ::: "memory");
  __builtin_amdgcn_s_barrier();

  for (int it = 0; it < (NT >> 1); it++) {
    int t = it * 2;
#pragma unroll
    for (int P = 0; P < 8; P++) {
      int ct = t + (P >> 2);
      int sel = ct & 1;
      if ((P & 3) == 0) {
#pragma unroll
        for (int i = 0; i < 4; i++) {
          int ra = wm * 128 + i * 16 + l16;
#pragma unroll
          for (int ks = 0; ks < 2; ks++)
            af[i][ks] = *(const bf16x8*)&As[sel][ra * 64 + (((ks * 4 + quad) ^ (ra & 7)) << 3)];
        }
#pragma unroll
        for (int j = 0; j < 2; j++) {
          int rb = wn * 64 + j * 16 + l16;
#pragma unroll
          for (int ks = 0; ks < 2; ks++)
            bv[j][ks] = *(const bf16x8*)&Bs[sel][rb * 64 + (((ks * 4 + quad) ^ (rb & 7)) << 3)];
        }
      } else if ((P & 3) == 1) {
#pragma unroll
        for (int j = 0; j < 2; j++) {
          int rb = wn * 64 + (2 + j) * 16 + l16;
#pragma unroll
          for (int ks = 0; ks < 2; ks++)
            bv[2 + j][ks] = *(const bf16x8*)&Bs[sel][rb * 64 + (((ks * 4 + quad) ^ (rb & 7)) << 3)];
        }
      } else if ((P & 3) == 2) {
#pragma unroll
        for (int i = 0; i < 4; i++) {
          int ra = wm * 128 + (4 + i) * 16 + l16;
#pragma unroll
          for (int ks = 0; ks < 2; ks++)
            af[i][ks] = *(const bf16x8*)&As[sel][ra * 64 + (((ks * 4 + quad) ^ (ra & 7)) << 3)];
        }
      }
      switch (P) {
        case 2: stage(Bbase, (unsigned short*)Bs, t + 2, 0); break;
        case 3: stage(Abase, (unsigned short*)As, t + 2, 0);
                stage(Bbase, (unsigned short*)Bs, t + 2, 1); break;
        case 4: stage(Abase, (unsigned short*)As, t + 2, 1); break;
        case 6: stage(Bbase, (unsigned short*)Bs, t + 3, 0);
                stage(Bbase, (unsigned short*)Bs, t + 3, 1); break;
        case 7: stage(Abase, (unsigned short*)As, t + 3, 0);
                stage(Abase, (unsigned short*)As, t + 3, 1); break;
        default: break;
      }
      __builtin_amdgcn_s_barrier();
      int qm = (P >> 1) & 1, qj = P & 1;
      __builtin_amdgcn_s_setprio(1);
#pragma unroll
      for (int i = 0; i < 4; i++)
#pragma unroll
        for (int j = 0; j < 2; j++)
#pragma unroll
          for (int ks = 0; ks < 2; ks++)
            acc[qm * 4 + i][qj * 2 + j] = __builtin_amdgcn_mfma_f32_16x16x32_bf16(
                bv[qj * 2 + j][ks], af[i][ks], acc[qm * 4 + i][qj * 2 + j], 0, 0, 0);
      __builtin_amdgcn_s_setprio(0);
      if (P == 3) asm volatile("s_waitcnt vmcnt(6)" ::: "memory");
      if (P == 7) asm volatile("s_waitcnt vmcnt(8)" ::: "memory");
      __builtin_amdgcn_s_barrier();
    }
  }
  asm volatile("s_waitcnt vmcnt(0)" ::: "memory");

  float* op = opart + (size_t)sp * M * N;
#pragma unroll
  for (int i = 0; i < 8; i++) {
    int m = m0 + wm * 128 + i * 16 + l16;
#pragma unroll
    for (int j = 0; j < 4; j++) {
      int nb = n0 + wn * 64 + j * 16 + quad * 4;
      *(f32x4*)&op[(size_t)m * N + nb] = acc[i][j];
    }
  }
}

// ---------- combine: out = p0 + p1 + bias + res (f32) ----------
__global__ __launch_bounds__(256)
void mlp2_combine_kernel(const float* __restrict__ p,
                         const float* __restrict__ bias,
                         const float* __restrict__ res,
                         float* __restrict__ out) {
  size_t tok = blockIdx.x;
  int d4 = threadIdx.x * 4;
  size_t off = tok * H + d4;
  float4 a = *(const float4*)&p[off];
  float4 c = *(const float4*)&p[(size_t)NTOK * H + off];
  float4 bb = *(const float4*)&bias[d4];
  float4 rv = *(const float4*)&res[off];
  float4 o4;
  o4.x = a.x + c.x + bb.x + rv.x;
  o4.y = a.y + c.y + bb.y + rv.y;
  o4.z = a.z + c.z + bb.z + rv.z;
  o4.w = a.w + c.w + bb.w + rv.w;
  *(float4*)&out[off] = o4;
}

// ---------- flash attention v12: barrier-free (no K-LDS staging) ----------
// R9 theory (m169 lesson): K is L2-resident (XCD-bh swizzle, per-XCD K+V
// working set = 4MB = one L2), so the LDS staging + its per-iteration
// __syncthreads were pure coupling overhead — the barrier existed ONLY to
// publish Ks. This version reads K fragments directly from global (L2-hit
// ~200cy); ZERO barriers in the whole kernel -> the 8 waves fully decouple
// and each wave's chain stalls hide under the other 3 waves on its SIMD.
// Cost: 8x K L2-traffic (~1TB aggregate ~ 10TB/s, well under 34.5 ceiling).
// Kept: exp2-prescaled Q (bare v_exp_f32), wave-private Ps (lgkm-only
// drains), setprio on MFMA, va reload per 32-kv half, XCD-bh swizzle.
__global__ __launch_bounds__(512, 4)
void flash_attn_kernel(const unsigned short* __restrict__ qkv,
                       const unsigned short* __restrict__ vt,
                       unsigned short* __restrict__ attn_out) {
  constexpr int LPs = 40;
  __shared__ __align__(16) unsigned short Ps[8 * 32 * LPs];
  int tid = threadIdx.x;
  int wave = tid >> 6, lane = tid & 63;
  int quad = lane >> 4, l16 = lane & 15;
  int d = blockIdx.x;
  int logical = (d & 7) * 64 + (d >> 3);  // XCD-bh grouping (bijective, 512=8*64)
  int bh = logical >> 3, qi = logical & 7;
  int b = bh >> 4, h = bh & 15;
  int qblk = qi * 256 + wave * 32;
  const size_t qrow = 3 * H;
  const size_t tok0 = (size_t)b * SEQ;
  const size_t vbase = (size_t)bh * HDIM * SEQ;
  unsigned short* Psw = Ps + wave * 32 * LPs;
  // K base for this (b,h): row r of K is at kbase + r*qrow
  const unsigned short* kbase = qkv + tok0 * qrow + H + h * HDIM;

  bf16x8 qb[2][2];
#pragma unroll
  for (int mb = 0; mb < 2; mb++)
#pragma unroll
    for (int ks = 0; ks < 2; ks++)
      qb[mb][ks] = *(const bf16x8*)&qkv[(tok0 + qblk + mb * 16 + l16) * qrow +
                                        h * HDIM + ks * 32 + quad * 8];

  float l_part[2] = {0.f, 0.f};
  f32x4 o_acc[2][4];
#pragma unroll
  for (int mb = 0; mb < 2; mb++)
#pragma unroll
    for (int db = 0; db < 4; db++) o_acc[mb][db] = (f32x4){0.f, 0.f, 0.f, 0.f};

  for (int kv0 = 0; kv0 < SEQ; kv0 += 64) {
    // V A-fragments for half 0; half 1 reloads after PV0
    bf16x8 va[4];
#pragma unroll
    for (int db = 0; db < 4; db++)
      va[db] = *(const bf16x8*)&vt[vbase + (size_t)(db * 16 + l16) * SEQ +
                                   kv0 + quad * 8];
#pragma unroll
    for (int half = 0; half < 2; half++) {
      // K fragments for this half, straight from L2 (no LDS, no barrier)
      bf16x8 ka[2][2];
#pragma unroll
      for (int nbl = 0; nbl < 2; nbl++) {
        int row = kv0 + (half * 2 + nbl) * 16 + l16;
#pragma unroll
        for (int ks = 0; ks < 2; ks++)
          ka[nbl][ks] = *(const bf16x8*)&kbase[(size_t)row * qrow + ks * 32 + quad * 8];
      }
#pragma unroll
      for (int nbl = 0; nbl < 2; nbl++) {
        int nb = half * 2 + nbl;
        f32x4 st[2];
#pragma unroll
        for (int mb = 0; mb < 2; mb++) st[mb] = (f32x4){0.f, 0.f, 0.f, 0.f};
        __builtin_amdgcn_s_setprio(1);
#pragma unroll
        for (int ks = 0; ks < 2; ks++)
#pragma unroll
          for (int mb = 0; mb < 2; mb++)
            st[mb] = __builtin_amdgcn_mfma_f32_16x16x32_bf16(ka[nbl][ks], qb[mb][ks], st[mb], 0, 0, 0);
        __builtin_amdgcn_s_setprio(0);
#pragma unroll
        for (int mb = 0; mb < 2; mb++) {
          // Q pre-scaled by 0.125*log2(e): P = 2^st, bare v_exp_f32.
          float p0, p1, p2, p3;
          asm("v_exp_f32 %0, %1" : "=v"(p0) : "v"(st[mb][0]));
          asm("v_exp_f32 %0, %1" : "=v"(p1) : "v"(st[mb][1]));
          asm("v_exp_f32 %0, %1" : "=v"(p2) : "v"(st[mb][2]));
          asm("v_exp_f32 %0, %1" : "=v"(p3) : "v"(st[mb][3]));
          l_part[mb] += (p0 + p1) + (p2 + p3);
          bf16x4 pk = {(__bf16)p0, (__bf16)p1, (__bf16)p2, (__bf16)p3};
          *(bf16x4*)&Psw[(mb * 16 + l16) * LPs + nb * 16 + quad * 4] = pk;
        }
      }
      // drain our wave's Ps writes for this half (wave-private, no barrier)
      __asm__ volatile("s_waitcnt lgkmcnt(0)" ::: "memory");
      bf16x8 pb[2];
#pragma unroll
      for (int mb = 0; mb < 2; mb++)
        pb[mb] = *(const bf16x8*)&Psw[(mb * 16 + l16) * LPs + half * 32 + quad * 8];
      __builtin_amdgcn_s_setprio(1);
#pragma unroll
      for (int db = 0; db < 4; db++)
#pragma unroll
        for (int mb = 0; mb < 2; mb++)
          o_acc[mb][db] = __builtin_amdgcn_mfma_f32_16x16x32_bf16(va[db], pb[mb],
                                                                  o_acc[mb][db], 0, 0, 0);
      __builtin_amdgcn_s_setprio(0);
      if (half == 0) {
        // reload va for half 1; latency hides under half 1's QK+exp phase
#pragma unroll
        for (int db = 0; db < 4; db++)
          va[db] = *(const bf16x8*)&vt[vbase + (size_t)(db * 16 + l16) * SEQ +
                                       kv0 + 32 + quad * 8];
      }
    }
  }
#pragma unroll
  for (int mb = 0; mb < 2; mb++) {
    l_part[mb] += __shfl_xor(l_part[mb], 16);
    l_part[mb] += __shfl_xor(l_part[mb], 32);
    l_part[mb] = 1.0f / l_part[mb];
  }
#pragma unroll
  for (int mb = 0; mb < 2; mb++) {
#pragma unroll
    for (int db = 0; db < 4; db++) {
      ushort4v o;
#pragma unroll
      for (int r = 0; r < 4; r++) o[r] = f2bf(o_acc[mb][db][r] * l_part[mb]);
      *(ushort4v*)&attn_out[(tok0 + qblk + mb * 16 + l16) * H + h * HDIM +
                            db * 16 + quad * 4] = o;
    }
  }
}

extern "C" void kernel_launch(void* const* d_in, const int* in_sizes, int n_in,
                              void* d_out, int out_size, void* d_ws, size_t ws_size,
                              hipStream_t stream) {
  const float* x = (const float*)d_in[0];
  const float* ln1_g = (const float*)d_in[1];
  const float* ln1_b = (const float*)d_in[2];
  const float* qkv_w = (const float*)d_in[3];
  const float* qkv_b = (const float*)d_in[4];
  const float* out_w = (const float*)d_in[5];
  const float* out_b = (const float*)d_in[6];
  const float* ln2_g = (const float*)d_in[7];
  const float* ln2_b = (const float*)d_in[8];
  const float* w1 = (const float*)d_in[9];
  const float* b1 = (const float*)d_in[10];
  const float* w2 = (const float*)d_in[11];
  const float* b2 = (const float*)d_in[12];
  float* outp = (float*)d_out;

  size_t off = 0;
  auto take = [&](size_t n) {
    char* p = (char*)d_ws + off;
    off += (n + 255) & ~(size_t)255;
    return p;
  };
  unsigned short* h1 = (unsigned short*)take((size_t)NTOK * H * 2);       // also h2
  unsigned short* qkvb = (unsigned short*)take((size_t)NTOK * 3 * H * 2); // qkv; later mid
  unsigned short* attn = (unsigned short*)take((size_t)NTOK * H * 2);
  float* x1 = (float*)take((size_t)NTOK * H * 4);
  unsigned short* qkvwt = (unsigned short*)take((size_t)3 * H * H * 2);
  unsigned short* outwt = (unsigned short*)take((size_t)H * H * 2);
  unsigned short* w1t = (unsigned short*)take((size_t)H * IDIM * 2);
  unsigned short* w2t = (unsigned short*)take((size_t)H * IDIM * 2);
  float* ppart = (float*)take((size_t)2 * NTOK * H * 4);  // 64MB MLP2 partials
  bool use_sk = off <= ws_size;
  unsigned short* h2 = h1;
  unsigned short* mid = qkvb;                // [NTOK][IDIM] aliases qkv+attn exactly
  unsigned short* vt = (unsigned short*)x1;  // vt dead before proj writes x1

  dim3 tb(32, 8);
  transpose_cast_all<<<dim3(12288), tb, 0, stream>>>(qkv_w, qkvwt, out_w, outwt,
                                                     w1, w1t, w2, w2t);

  layernorm_kernel<<<NTOK, 256, 0, stream>>>(x, ln1_g, ln1_b, h1);
  gemm256_kernel<0><<<dim3(3 * H / 256, NTOK / 256), 512, 0, stream>>>(
      h1, qkvwt, qkv_b, qkvb, vt, NTOK, 3 * H, H);
  flash_attn_kernel<<<dim3(SEQ / 256 * BATCH * NHEAD), 512, 0, stream>>>(qkvb, vt, attn);
  gemm_bt_kernel<2><<<dim3(H / 128, NTOK / 128), 256, 0, stream>>>(
      attn, outwt, out_b, x, x1, nullptr, NTOK, H, H);
  layernorm_kernel<<<NTOK, 256, 0, stream>>>(x1, ln2_g, ln2_b, h2);
  gemm256_kernel<1><<<dim3(IDIM / 256, NTOK / 256), 512, 0, stream>>>(
      h2, w1t, b1, mid, nullptr, NTOK, IDIM, H);
  if (use_sk) {
    gemm256_sk_kernel<<<dim3(256), 512, 0, stream>>>(mid, w2t, ppart, NTOK, H, IDIM, IDIM / 2);
    mlp2_combine_kernel<<<dim3(NTOK), 256, 0, stream>>>(ppart, b2, x1, outp);
  } else {
    gemm_bt_kernel<2><<<dim3(H / 128, NTOK / 128), 256, 0, stream>>>(
        mid, w2t, b2, x1, outp, nullptr, NTOK, H, IDIM);
  }
}

// Round 10
// 580.551 us; speedup vs baseline: 1.1769x; 1.1769x over previous
//
#include <hip/hip_runtime.h>
#include <math.h>

#define H 1024
#define NHEAD 16
#define HDIM 64
#define IDIM 4096
#define BATCH 4
#define SEQ 2048
#define NTOK 8192
#define LN_EPS 1e-5f

// 0.125 * log2(e): folded into Q at QKV-GEMM epilogue so attention's softmax
// is a raw v_exp_f32 (2^x) with zero preceding VALU muls.
#define QK_EXP2_SCALE 0.18033688011112042f

typedef __bf16 bf16x8 __attribute__((ext_vector_type(8)));
typedef __bf16 bf16x4 __attribute__((ext_vector_type(4)));
typedef float f32x4 __attribute__((ext_vector_type(4)));
typedef unsigned short ushort8 __attribute__((ext_vector_type(8)));
typedef unsigned short ushort4v __attribute__((ext_vector_type(4)));

__device__ __forceinline__ unsigned short f2bf(float f) {
  union { float f; unsigned int u; } v; v.f = f;
  unsigned int u = v.u;
  return (unsigned short)((u + 0x7FFFu + ((u >> 16) & 1u)) >> 16);
}

// ---------- fused transpose + cast: 4 weight matrices in ONE launch ----------
__global__ void transpose_cast_all(const float* __restrict__ W0, unsigned short* __restrict__ T0,
                                   const float* __restrict__ W1, unsigned short* __restrict__ T1,
                                   const float* __restrict__ W2, unsigned short* __restrict__ T2,
                                   const float* __restrict__ W3, unsigned short* __restrict__ T3) {
  __shared__ unsigned short tile[32][33];
  int bid = blockIdx.x;
  const float* W;
  unsigned short* Wt;
  int K, N, ntx, local;
  if (bid < 3072) {
    W = W0; Wt = T0; K = H; N = 3 * H; ntx = 3 * H / 32; local = bid;
  } else if (bid < 4096) {
    W = W1; Wt = T1; K = H; N = H; ntx = H / 32; local = bid - 3072;
  } else if (bid < 8192) {
    W = W2; Wt = T2; K = H; N = IDIM; ntx = IDIM / 32; local = bid - 4096;
  } else {
    W = W3; Wt = T3; K = IDIM; N = H; ntx = H / 32; local = bid - 8192;
  }
  int n0 = (local % ntx) * 32, k0 = (local / ntx) * 32;
  int tx = threadIdx.x, ty = threadIdx.y;  // 32 x 8
#pragma unroll
  for (int i = 0; i < 4; i++) {
    int k = ty + i * 8;
    tile[tx][k] = f2bf(W[(size_t)(k0 + k) * N + n0 + tx]);
  }
  __syncthreads();
#pragma unroll
  for (int i = 0; i < 4; i++) {
    int n = ty + i * 8;
    Wt[(size_t)(n0 + n) * K + k0 + tx] = tile[n][tx];
  }
}

// ---------- layernorm: f32 [rows][H] -> bf16 ----------
__global__ __launch_bounds__(256)
void layernorm_kernel(const float* __restrict__ x, const float* __restrict__ g,
                      const float* __restrict__ b, unsigned short* __restrict__ out) {
  __shared__ float sb[4];
  int row = blockIdx.x;
  int tid = threadIdx.x;
  const float4* xr = (const float4*)(x + (size_t)row * H);
  float4 v = xr[tid];
  float s = v.x + v.y + v.z + v.w;
#pragma unroll
  for (int o = 32; o > 0; o >>= 1) s += __shfl_down(s, o);
  if ((tid & 63) == 0) sb[tid >> 6] = s;
  __syncthreads();
  float mu = (sb[0] + sb[1] + sb[2] + sb[3]) * (1.0f / H);
  __syncthreads();
  float dx = v.x - mu, dy = v.y - mu, dz = v.z - mu, dw = v.w - mu;
  float s2 = dx * dx + dy * dy + dz * dz + dw * dw;
#pragma unroll
  for (int o = 32; o > 0; o >>= 1) s2 += __shfl_down(s2, o);
  if ((tid & 63) == 0) sb[tid >> 6] = s2;
  __syncthreads();
  float var = (sb[0] + sb[1] + sb[2] + sb[3]) * (1.0f / H);
  float rs = rsqrtf(var + LN_EPS);
  float4 gv = ((const float4*)g)[tid];
  float4 bv = ((const float4*)b)[tid];
  ushort4v ov;
  ov[0] = f2bf(dx * rs * gv.x + bv.x);
  ov[1] = f2bf(dy * rs * gv.y + bv.y);
  ov[2] = f2bf(dz * rs * gv.z + bv.z);
  ov[3] = f2bf(dw * rs * gv.w + bv.w);
  ((ushort4v*)(out + (size_t)row * H))[tid] = ov;
}

// ---------- GEMM 128^2 (proven single-barrier structure) ----------
// proj + MLP2 fallback. m-grouped XCD swizzle (R8, validated).
template <int EPI>
__global__ __launch_bounds__(256)
void gemm_bt_kernel(const unsigned short* __restrict__ A,
                    const unsigned short* __restrict__ Bt,
                    const float* __restrict__ bias,
                    const float* __restrict__ res,
                    void* __restrict__ out, unsigned short* __restrict__ vt_out,
                    int M, int N, int K) {
  __shared__ __align__(16) unsigned short As[2][128 * 32];
  __shared__ __align__(16) unsigned short Bs[2][128 * 32];
  int tid = threadIdx.x;
  int wave = tid >> 6, lane = tid & 63;
  int quad = lane >> 4, l16 = lane & 15;
  int wm = wave >> 1, wn = wave & 1;
  int nwg = gridDim.x * gridDim.y;
  int dlin = blockIdx.y * gridDim.x + blockIdx.x;
  int swz = (nwg & 7) ? dlin : ((dlin & 7) * (nwg >> 3) + (dlin >> 3));
  int mt = swz / gridDim.x, nt = swz % gridDim.x;  // m-major decode
  int m0 = mt * 128, n0 = nt * 128;
  f32x4 acc[4][4];
#pragma unroll
  for (int i = 0; i < 4; i++)
#pragma unroll
    for (int j = 0; j < 4; j++) acc[i][j] = (f32x4){0.f, 0.f, 0.f, 0.f};

  int rl = (lane >> 2);
  int cphys = lane & 3;

  auto stage = [&](int k0, int sel) {
#pragma unroll
    for (int t = 0; t < 2; t++) {
      int ch = wave * 2 + t;
      int rloc = ch * 16 + rl;
      int clog = cphys ^ ((rloc >> 1) & 3);
      const unsigned short* ga = A + (size_t)(m0 + rloc) * K + k0 + clog * 8;
      __builtin_amdgcn_global_load_lds(
          (const __attribute__((address_space(1))) unsigned int*)ga,
          (__attribute__((address_space(3))) unsigned int*)(&As[sel][ch * 512]), 16, 0, 0);
      const unsigned short* gb = Bt + (size_t)(n0 + rloc) * K + k0 + clog * 8;
      __builtin_amdgcn_global_load_lds(
          (const __attribute__((address_space(1))) unsigned int*)gb,
          (__attribute__((address_space(3))) unsigned int*)(&Bs[sel][ch * 512]), 16, 0, 0);
    }
  };

  stage(0, 0);
  for (int k0 = 0; k0 < K; k0 += 32) {
    int sel = (k0 >> 5) & 1;
    __syncthreads();
    if (k0 + 32 < K) stage(k0 + 32, sel ^ 1);
    bf16x8 af[4], bfv[4];
#pragma unroll
    for (int i = 0; i < 4; i++) {
      int ra = wm * 64 + i * 16 + l16;
      af[i] = *(const bf16x8*)&As[sel][ra * 32 + ((quad ^ ((ra >> 1) & 3)) << 3)];
      int rb = wn * 64 + i * 16 + l16;
      bfv[i] = *(const bf16x8*)&Bs[sel][rb * 32 + ((quad ^ ((rb >> 1) & 3)) << 3)];
    }
#pragma unroll
    for (int i = 0; i < 4; i++)
#pragma unroll
      for (int j = 0; j < 4; j++)
        acc[i][j] = __builtin_amdgcn_mfma_f32_16x16x32_bf16(bfv[j], af[i], acc[i][j], 0, 0, 0);
  }
#pragma unroll
  for (int i = 0; i < 4; i++) {
    int m = m0 + wm * 64 + i * 16 + l16;
#pragma unroll
    for (int j = 0; j < 4; j++) {
      int nb = n0 + wn * 64 + j * 16 + quad * 4;
      float4 bv4 = *(const float4*)&bias[nb];
      float v0 = acc[i][j][0] + bv4.x;
      float v1 = acc[i][j][1] + bv4.y;
      float v2 = acc[i][j][2] + bv4.z;
      float v3 = acc[i][j][3] + bv4.w;
      size_t off = (size_t)m * N + nb;
      float4 rv = *(const float4*)&res[off];
      float4 o4;
      o4.x = v0 + rv.x; o4.y = v1 + rv.y; o4.z = v2 + rv.z; o4.w = v3 + rv.w;
      *(float4*)&((float*)out)[off] = o4;
    }
  }
}

// ---------- GEMM 256^2 8-phase (race-fixed ledger, see R5 notes) ----------
template <int EPI>
__global__ __launch_bounds__(512, 2)
void gemm256_kernel(const unsigned short* __restrict__ A,
                    const unsigned short* __restrict__ Bt,
                    const float* __restrict__ bias,
                    void* __restrict__ out, unsigned short* __restrict__ vt_out,
                    int M, int N, int K) {
  __shared__ __align__(16) unsigned short As[2][256 * 64];
  __shared__ __align__(16) unsigned short Bs[2][256 * 64];
  int tid = threadIdx.x;
  int wave = tid >> 6, lane = tid & 63;
  int quad = lane >> 4, l16 = lane & 15;
  int wm = wave >> 2, wn = wave & 3;
  int nwg = gridDim.x * gridDim.y;
  int dlin = blockIdx.y * gridDim.x + blockIdx.x;
  int swz = (dlin & 7) * (nwg >> 3) + (dlin >> 3);
  int nm = gridDim.y;  // M/256
  int mt = swz % nm, nt = swz / nm;
  int m0 = mt * 256, n0 = nt * 256;
  int NT = K >> 6;

  const unsigned short* Abase = A + (size_t)m0 * K;
  const unsigned short* Bbase = Bt + (size_t)n0 * K;

  int srow = lane >> 3;
  int schunk = (lane & 7) ^ srow;

  auto stage = [&](const unsigned short* gbase, unsigned short* lbase, int tile,
                   int half) {
    int kt = tile < NT ? tile : NT - 1;
    int k0 = kt << 6;
    unsigned short* lb = lbase + (size_t)(tile & 1) * (256 * 64);
#pragma unroll
    for (int L = 0; L < 2; L++) {
      int rloc = half * 128 + L * 64 + wave * 8 + srow;
      const unsigned short* g = gbase + (size_t)rloc * K + k0 + schunk * 8;
      __builtin_amdgcn_global_load_lds(
          (const __attribute__((address_space(1))) unsigned int*)g,
          (__attribute__((address_space(3))) unsigned int*)(lb + (size_t)(half * 128 + L * 64 + wave * 8) * 64),
          16, 0, 0);
    }
  };

  f32x4 acc[8][4];
#pragma unroll
  for (int i = 0; i < 8; i++)
#pragma unroll
    for (int j = 0; j < 4; j++) acc[i][j] = (f32x4){0.f, 0.f, 0.f, 0.f};
  bf16x8 af[4][2];
  bf16x8 bv[4][2];

  stage(Abase, (unsigned short*)As, 0, 0);
  stage(Bbase, (unsigned short*)Bs, 0, 0);
  stage(Abase, (unsigned short*)As, 0, 1);
  stage(Bbase, (unsigned short*)Bs, 0, 1);
  stage(Abase, (unsigned short*)As, 1, 0);
  stage(Bbase, (unsigned short*)Bs, 1, 0);
  stage(Abase, (unsigned short*)As, 1, 1);
  stage(Bbase, (unsigned short*)Bs, 1, 1);
  asm volatile("s_waitcnt vmcnt(8)" ::: "memory");
  __builtin_amdgcn_s_barrier();

  for (int it = 0; it < (NT >> 1); it++) {
    int t = it * 2;
#pragma unroll
    for (int P = 0; P < 8; P++) {
      int ct = t + (P >> 2);
      int sel = ct & 1;
      if ((P & 3) == 0) {
#pragma unroll
        for (int i = 0; i < 4; i++) {
          int ra = wm * 128 + i * 16 + l16;
#pragma unroll
          for (int ks = 0; ks < 2; ks++)
            af[i][ks] = *(const bf16x8*)&As[sel][ra * 64 + (((ks * 4 + quad) ^ (ra & 7)) << 3)];
        }
#pragma unroll
        for (int j = 0; j < 2; j++) {
          int rb = wn * 64 + j * 16 + l16;
#pragma unroll
          for (int ks = 0; ks < 2; ks++)
            bv[j][ks] = *(const bf16x8*)&Bs[sel][rb * 64 + (((ks * 4 + quad) ^ (rb & 7)) << 3)];
        }
      } else if ((P & 3) == 1) {
#pragma unroll
        for (int j = 0; j < 2; j++) {
          int rb = wn * 64 + (2 + j) * 16 + l16;
#pragma unroll
          for (int ks = 0; ks < 2; ks++)
            bv[2 + j][ks] = *(const bf16x8*)&Bs[sel][rb * 64 + (((ks * 4 + quad) ^ (rb & 7)) << 3)];
        }
      } else if ((P & 3) == 2) {
#pragma unroll
        for (int i = 0; i < 4; i++) {
          int ra = wm * 128 + (4 + i) * 16 + l16;
#pragma unroll
          for (int ks = 0; ks < 2; ks++)
            af[i][ks] = *(const bf16x8*)&As[sel][ra * 64 + (((ks * 4 + quad) ^ (ra & 7)) << 3)];
        }
      }
      switch (P) {
        case 2: stage(Bbase, (unsigned short*)Bs, t + 2, 0); break;
        case 3: stage(Abase, (unsigned short*)As, t + 2, 0);
                stage(Bbase, (unsigned short*)Bs, t + 2, 1); break;
        case 4: stage(Abase, (unsigned short*)As, t + 2, 1); break;
        case 6: stage(Bbase, (unsigned short*)Bs, t + 3, 0);
                stage(Bbase, (unsigned short*)Bs, t + 3, 1); break;
        case 7: stage(Abase, (unsigned short*)As, t + 3, 0);
                stage(Abase, (unsigned short*)As, t + 3, 1); break;
        default: break;
      }
      __builtin_amdgcn_s_barrier();
      int qm = (P >> 1) & 1, qj = P & 1;
      __builtin_amdgcn_s_setprio(1);
#pragma unroll
      for (int i = 0; i < 4; i++)
#pragma unroll
        for (int j = 0; j < 2; j++)
#pragma unroll
          for (int ks = 0; ks < 2; ks++)
            acc[qm * 4 + i][qj * 2 + j] = __builtin_amdgcn_mfma_f32_16x16x32_bf16(
                bv[qj * 2 + j][ks], af[i][ks], acc[qm * 4 + i][qj * 2 + j], 0, 0, 0);
      __builtin_amdgcn_s_setprio(0);
      if (P == 3) asm volatile("s_waitcnt vmcnt(6)" ::: "memory");
      if (P == 7) asm volatile("s_waitcnt vmcnt(8)" ::: "memory");
      __builtin_amdgcn_s_barrier();
    }
  }
  asm volatile("s_waitcnt vmcnt(0)" ::: "memory");

  bool vslice = (EPI == 0) && (vt_out != nullptr) && (n0 >= 2 * H);
#pragma unroll
  for (int i = 0; i < 8; i++) {
    int m = m0 + wm * 128 + i * 16 + l16;
#pragma unroll
    for (int j = 0; j < 4; j++) {
      int nb = n0 + wn * 64 + j * 16 + quad * 4;
      float4 bv4 = *(const float4*)&bias[nb];
      float v0 = acc[i][j][0] + bv4.x;
      float v1 = acc[i][j][1] + bv4.y;
      float v2 = acc[i][j][2] + bv4.z;
      float v3 = acc[i][j][3] + bv4.w;
      size_t off = (size_t)m * N + nb;
      if (EPI == 0) {
        if (vslice) {
          int bb = m >> 11, s = m & (SEQ - 1);
          int cb = nb - 2 * H;
          int hh = cb >> 6, dd = cb & 63;
          size_t base = ((size_t)(bb * NHEAD + hh) * HDIM + dd) * SEQ + s;
          vt_out[base] = f2bf(v0);
          vt_out[base + SEQ] = f2bf(v1);
          vt_out[base + 2 * SEQ] = f2bf(v2);
          vt_out[base + 3 * SEQ] = f2bf(v3);
        } else {
          if (n0 < H) {
            v0 *= QK_EXP2_SCALE; v1 *= QK_EXP2_SCALE;
            v2 *= QK_EXP2_SCALE; v3 *= QK_EXP2_SCALE;
          }
          bf16x4 pk = {(__bf16)v0, (__bf16)v1, (__bf16)v2, (__bf16)v3};
          *(bf16x4*)&((unsigned short*)out)[off] = pk;
        }
      } else {
        float g0 = v0 / (1.f + __expf(-1.5957691216057308f * (v0 + 0.044715f * v0 * v0 * v0)));
        float g1 = v1 / (1.f + __expf(-1.5957691216057308f * (v1 + 0.044715f * v1 * v1 * v1)));
        float g2 = v2 / (1.f + __expf(-1.5957691216057308f * (v2 + 0.044715f * v2 * v2 * v2)));
        float g3 = v3 / (1.f + __expf(-1.5957691216057308f * (v3 + 0.044715f * v3 * v3 * v3)));
        bf16x4 pk = {(__bf16)g0, (__bf16)g1, (__bf16)g2, (__bf16)g3};
        *(bf16x4*)&((unsigned short*)out)[off] = pk;
      }
    }
  }
}

// ---------- GEMM 256^2 split-K=2 (MLP2): f32 partials (R8, validated) ----------
__global__ __launch_bounds__(512, 2)
void gemm256_sk_kernel(const unsigned short* __restrict__ A,
                       const unsigned short* __restrict__ Bt,
                       float* __restrict__ opart,
                       int M, int N, int Kf, int KL) {
  __shared__ __align__(16) unsigned short As[2][256 * 64];
  __shared__ __align__(16) unsigned short Bs[2][256 * 64];
  int tid = threadIdx.x;
  int wave = tid >> 6, lane = tid & 63;
  int quad = lane >> 4, l16 = lane & 15;
  int wm = wave >> 2, wn = wave & 3;
  int d = blockIdx.x;
  int swz = (d & 7) * 32 + (d >> 3);
  int sp = swz >> 7;
  int rem = swz & 127;
  int mt = rem >> 2, nt = rem & 3;
  int m0 = mt * 256, n0 = nt * 256;
  int NT = KL >> 6;
  int k0g = sp * KL;

  const unsigned short* Abase = A + (size_t)m0 * Kf + k0g;
  const unsigned short* Bbase = Bt + (size_t)n0 * Kf + k0g;

  int srow = lane >> 3;
  int schunk = (lane & 7) ^ srow;

  auto stage = [&](const unsigned short* gbase, unsigned short* lbase, int tile,
                   int half) {
    int kt = tile < NT ? tile : NT - 1;
    int k0 = kt << 6;
    unsigned short* lb = lbase + (size_t)(tile & 1) * (256 * 64);
#pragma unroll
    for (int L = 0; L < 2; L++) {
      int rloc = half * 128 + L * 64 + wave * 8 + srow;
      const unsigned short* g = gbase + (size_t)rloc * Kf + k0 + schunk * 8;
      __builtin_amdgcn_global_load_lds(
          (const __attribute__((address_space(1))) unsigned int*)g,
          (__attribute__((address_space(3))) unsigned int*)(lb + (size_t)(half * 128 + L * 64 + wave * 8) * 64),
          16, 0, 0);
    }
  };

  f32x4 acc[8][4];
#pragma unroll
  for (int i = 0; i < 8; i++)
#pragma unroll
    for (int j = 0; j < 4; j++) acc[i][j] = (f32x4){0.f, 0.f, 0.f, 0.f};
  bf16x8 af[4][2];
  bf16x8 bv[4][2];

  stage(Abase, (unsigned short*)As, 0, 0);
  stage(Bbase, (unsigned short*)Bs, 0, 0);
  stage(Abase, (unsigned short*)As, 0, 1);
  stage(Bbase, (unsigned short*)Bs, 0, 1);
  stage(Abase, (unsigned short*)As, 1, 0);
  stage(Bbase, (unsigned short*)Bs, 1, 0);
  stage(Abase, (unsigned short*)As, 1, 1);
  stage(Bbase, (unsigned short*)Bs, 1, 1);
  asm volatile("s_waitcnt vmcnt(8)" ::: "memory");
  __builtin_amdgcn_s_barrier();

  for (int it = 0; it < (NT >> 1); it++) {
    int t = it * 2;
#pragma unroll
    for (int P = 0; P < 8; P++) {
      int ct = t + (P >> 2);
      int sel = ct & 1;
      if ((P & 3) == 0) {
#pragma unroll
        for (int i = 0; i < 4; i++) {
          int ra = wm * 128 + i * 16 + l16;
#pragma unroll
          for (int ks = 0; ks < 2; ks++)
            af[i][ks] = *(const bf16x8*)&As[sel][ra * 64 + (((ks * 4 + quad) ^ (ra & 7)) << 3)];
        }
#pragma unroll
        for (int j = 0; j < 2; j++) {
          int rb = wn * 64 + j * 16 + l16;
#pragma unroll
          for (int ks = 0; ks < 2; ks++)
            bv[j][ks] = *(const bf16x8*)&Bs[sel][rb * 64 + (((ks * 4 + quad) ^ (rb & 7)) << 3)];
        }
      } else if ((P & 3) == 1) {
#pragma unroll
        for (int j = 0; j < 2; j++) {
          int rb = wn * 64 + (2 + j) * 16 + l16;
#pragma unroll
          for (int ks = 0; ks < 2; ks++)
            bv[2 + j][ks] = *(const bf16x8*)&Bs[sel][rb * 64 + (((ks * 4 + quad) ^ (rb & 7)) << 3)];
        }
      } else if ((P & 3) == 2) {
#pragma unroll
        for (int i = 0; i < 4; i++) {
          int ra = wm * 128 + (4 + i) * 16 + l16;
#pragma unroll
          for (int ks = 0; ks < 2; ks++)
            af[i][ks] = *(const bf16x8*)&As[sel][ra * 64 + (((ks * 4 + quad) ^ (ra & 7)) << 3)];
        }
      }
      switch (P) {
        case 2: stage(Bbase, (unsigned short*)Bs, t + 2, 0); break;
        case 3: stage(Abase, (unsigned short*)As, t + 2, 0);
                stage(Bbase, (unsigned short*)Bs, t + 2, 1); break;
        case 4: stage(Abase, (unsigned short*)As, t + 2, 1); break;
        case 6: stage(Bbase, (unsigned short*)Bs, t + 3, 0);
                stage(Bbase, (unsigned short*)Bs, t + 3, 1); break;
        case 7: stage(Abase, (unsigned short*)As, t + 3, 0);
                stage(Abase, (unsigned short*)As, t + 3, 1); break;
        default: break;
      }
      __builtin_amdgcn_s_barrier();
      int qm = (P >> 1) & 1, qj = P & 1;
      __builtin_amdgcn_s_setprio(1);
#pragma unroll
      for (int i = 0; i < 4; i++)
#pragma unroll
        for (int j = 0; j < 2; j++)
#pragma unroll
          for (int ks = 0; ks < 2; ks++)
            acc[qm * 4 + i][qj * 2 + j] = __builtin_amdgcn_mfma_f32_16x16x32_bf16(
                bv[qj * 2 + j][ks], af[i][ks], acc[qm * 4 + i][qj * 2 + j], 0, 0, 0);
      __builtin_amdgcn_s_setprio(0);
      if (P == 3) asm volatile("s_waitcnt vmcnt(6)" ::: "memory");
      if (P == 7) asm volatile("s_waitcnt vmcnt(8)" ::: "memory");
      __builtin_amdgcn_s_barrier();
    }
  }
  asm volatile("s_waitcnt vmcnt(0)" ::: "memory");

  float* op = opart + (size_t)sp * M * N;
#pragma unroll
  for (int i = 0; i < 8; i++) {
    int m = m0 + wm * 128 + i * 16 + l16;
#pragma unroll
    for (int j = 0; j < 4; j++) {
      int nb = n0 + wn * 64 + j * 16 + quad * 4;
      *(f32x4*)&op[(size_t)m * N + nb] = acc[i][j];
    }
  }
}

// ---------- combine: out = p0 + p1 + bias + res (f32) ----------
__global__ __launch_bounds__(256)
void mlp2_combine_kernel(const float* __restrict__ p,
                         const float* __restrict__ bias,
                         const float* __restrict__ res,
                         float* __restrict__ out) {
  size_t tok = blockIdx.x;
  int d4 = threadIdx.x * 4;
  size_t off = tok * H + d4;
  float4 a = *(const float4*)&p[off];
  float4 c = *(const float4*)&p[(size_t)NTOK * H + off];
  float4 bb = *(const float4*)&bias[d4];
  float4 rv = *(const float4*)&res[off];
  float4 o4;
  o4.x = a.x + c.x + bb.x + rv.x;
  o4.y = a.y + c.y + bb.y + rv.y;
  o4.z = a.z + c.z + bb.z + rv.z;
  o4.w = a.w + c.w + bb.w + rv.w;
  *(float4*)&out[off] = o4;
}

// ---------- flash attention v13: R8 structure + 128-row K staging ----------
// R9 post-mortem: direct-from-global K reads (16B x 16 lanes at 6KB row
// stride) destroyed coalescing -> 245us. Staging via global_load_lds is the
// right structure (coalesced 128B rows). This version restores R8 and halves
// the barrier frequency: stage 128 kv rows per tile (2 gload_lds/thread),
// barrier every 128 kv (16 total vs 32). Each staged tile now has a full
// 4-half compute phase in flight before its vmcnt(0) drain, and the 8-wave
// coupling points halve. Ps slot scheme: halves {0,2}->slot0, {1,3}->slot1
// (slot data dead after its PV; wave-private sequential => safe, same
// overlap-compression argument as LPs=40).
// Kept: exp2-prescaled Q (bare v_exp_f32), setprio on MFMA, va reload per
// 32-kv half, XCD-bh swizzle (512=8*64), wave-private Ps lgkm-only drains.
__global__ __launch_bounds__(512, 4)
void flash_attn_kernel(const unsigned short* __restrict__ qkv,
                       const unsigned short* __restrict__ vt,
                       unsigned short* __restrict__ attn_out) {
  constexpr int LPs = 40;
  __shared__ __align__(16) unsigned short Ks[2][128 * 64];
  __shared__ __align__(16) unsigned short Ps[8 * 32 * LPs];
  int tid = threadIdx.x;
  int wave = tid >> 6, lane = tid & 63;
  int quad = lane >> 4, l16 = lane & 15;
  int d = blockIdx.x;
  int logical = (d & 7) * 64 + (d >> 3);  // XCD-bh grouping (bijective, 512=8*64)
  int bh = logical >> 3, qi = logical & 7;
  int b = bh >> 4, h = bh & 15;
  int qblk = qi * 256 + wave * 32;
  const size_t qrow = 3 * H;
  const size_t tok0 = (size_t)b * SEQ;
  const size_t vbase = (size_t)bh * HDIM * SEQ;
  unsigned short* Psw = Ps + wave * 32 * LPs;

  bf16x8 qb[2][2];
#pragma unroll
  for (int mb = 0; mb < 2; mb++)
#pragma unroll
    for (int ks = 0; ks < 2; ks++)
      qb[mb][ks] = *(const bf16x8*)&qkv[(tok0 + qblk + mb * 16 + l16) * qrow +
                                        h * HDIM + ks * 32 + quad * 8];

  float l_part[2] = {0.f, 0.f};
  f32x4 o_acc[2][4];
#pragma unroll
  for (int mb = 0; mb < 2; mb++)
#pragma unroll
    for (int db = 0; db < 4; db++) o_acc[mb][db] = (f32x4){0.f, 0.f, 0.f, 0.f};

  int srow = lane >> 3;            // 0..7: row within 8-row staging group
  int schunk = (lane & 7) ^ srow;  // swizzled 16B source chunk

  // stage 128 K rows (wave stages rows [wave*16, wave*16+16), 2 chunks)
  auto stageK = [&](int kvbase, unsigned short* dst) {
#pragma unroll
    for (int c = 0; c < 2; c++) {
      int rbase = wave * 16 + c * 8;
      const unsigned short* ga =
          &qkv[(tok0 + kvbase + rbase + srow) * qrow + H + h * HDIM + schunk * 8];
      __builtin_amdgcn_global_load_lds(
          (const __attribute__((address_space(1))) unsigned int*)ga,
          (__attribute__((address_space(3))) unsigned int*)(dst + rbase * 64), 16, 0, 0);
    }
  };

  stageK(0, Ks[0]);  // prologue

  for (int kv0 = 0; kv0 < SEQ; kv0 += 128) {
    int buf = (kv0 >> 7) & 1;
    const unsigned short* Kb = Ks[buf];
    unsigned short* Kn = Ks[buf ^ 1];
    __syncthreads();  // vmcnt(0) drain = Ks[buf] staged; fences Kn readers
    // V A-fragments for half 0; each later half reloads after prior PV
    bf16x8 va[4];
#pragma unroll
    for (int db = 0; db < 4; db++)
      va[db] = *(const bf16x8*)&vt[vbase + (size_t)(db * 16 + l16) * SEQ +
                                   kv0 + quad * 8];
    if (kv0 + 128 < SEQ) stageK(kv0 + 128, Kn);
    // 4 halves of 32 kv each; Ps slot = half&1
#pragma unroll
    for (int half = 0; half < 4; half++) {
      int slot = half & 1;
#pragma unroll
      for (int nbl = 0; nbl < 2; nbl++) {
        int row = half * 32 + nbl * 16 + l16;  // 0..127 within tile
        bf16x8 ka[2];
#pragma unroll
        for (int ks = 0; ks < 2; ks++) {
          int pc = (ks * 4 + quad) ^ (row & 7);
          ka[ks] = *(const bf16x8*)&Kb[row * 64 + pc * 8];
        }
        f32x4 st[2];
#pragma unroll
        for (int mb = 0; mb < 2; mb++) st[mb] = (f32x4){0.f, 0.f, 0.f, 0.f};
        __builtin_amdgcn_s_setprio(1);
#pragma unroll
        for (int ks = 0; ks < 2; ks++)
#pragma unroll
          for (int mb = 0; mb < 2; mb++)
            st[mb] = __builtin_amdgcn_mfma_f32_16x16x32_bf16(ka[ks], qb[mb][ks], st[mb], 0, 0, 0);
        __builtin_amdgcn_s_setprio(0);
#pragma unroll
        for (int mb = 0; mb < 2; mb++) {
          // Q pre-scaled by 0.125*log2(e): P = 2^st, bare v_exp_f32.
          float p0, p1, p2, p3;
          asm("v_exp_f32 %0, %1" : "=v"(p0) : "v"(st[mb][0]));
          asm("v_exp_f32 %0, %1" : "=v"(p1) : "v"(st[mb][1]));
          asm("v_exp_f32 %0, %1" : "=v"(p2) : "v"(st[mb][2]));
          asm("v_exp_f32 %0, %1" : "=v"(p3) : "v"(st[mb][3]));
          l_part[mb] += (p0 + p1) + (p2 + p3);
          bf16x4 pk = {(__bf16)p0, (__bf16)p1, (__bf16)p2, (__bf16)p3};
          *(bf16x4*)&Psw[(mb * 16 + l16) * LPs + slot * 32 + nbl * 16 + quad * 4] = pk;
        }
      }
      // drain our wave's Ps writes for this half (wave-private, no barrier)
      __asm__ volatile("s_waitcnt lgkmcnt(0)" ::: "memory");
      bf16x8 pb[2];
#pragma unroll
      for (int mb = 0; mb < 2; mb++)
        pb[mb] = *(const bf16x8*)&Psw[(mb * 16 + l16) * LPs + slot * 32 + quad * 8];
      __builtin_amdgcn_s_setprio(1);
#pragma unroll
      for (int db = 0; db < 4; db++)
#pragma unroll
        for (int mb = 0; mb < 2; mb++)
          o_acc[mb][db] = __builtin_amdgcn_mfma_f32_16x16x32_bf16(va[db], pb[mb],
                                                                  o_acc[mb][db], 0, 0, 0);
      __builtin_amdgcn_s_setprio(0);
      if (half < 3) {
        // reload va for next half; latency hides under next QK+exp phase
#pragma unroll
        for (int db = 0; db < 4; db++)
          va[db] = *(const bf16x8*)&vt[vbase + (size_t)(db * 16 + l16) * SEQ +
                                       kv0 + (half + 1) * 32 + quad * 8];
      }
    }
  }
#pragma unroll
  for (int mb = 0; mb < 2; mb++) {
    l_part[mb] += __shfl_xor(l_part[mb], 16);
    l_part[mb] += __shfl_xor(l_part[mb], 32);
    l_part[mb] = 1.0f / l_part[mb];
  }
#pragma unroll
  for (int mb = 0; mb < 2; mb++) {
#pragma unroll
    for (int db = 0; db < 4; db++) {
      ushort4v o;
#pragma unroll
      for (int r = 0; r < 4; r++) o[r] = f2bf(o_acc[mb][db][r] * l_part[mb]);
      *(ushort4v*)&attn_out[(tok0 + qblk + mb * 16 + l16) * H + h * HDIM +
                            db * 16 + quad * 4] = o;
    }
  }
}

extern "C" void kernel_launch(void* const* d_in, const int* in_sizes, int n_in,
                              void* d_out, int out_size, void* d_ws, size_t ws_size,
                              hipStream_t stream) {
  const float* x = (const float*)d_in[0];
  const float* ln1_g = (const float*)d_in[1];
  const float* ln1_b = (const float*)d_in[2];
  const float* qkv_w = (const float*)d_in[3];
  const float* qkv_b = (const float*)d_in[4];
  const float* out_w = (const float*)d_in[5];
  const float* out_b = (const float*)d_in[6];
  const float* ln2_g = (const float*)d_in[7];
  const float* ln2_b = (const float*)d_in[8];
  const float* w1 = (const float*)d_in[9];
  const float* b1 = (const float*)d_in[10];
  const float* w2 = (const float*)d_in[11];
  const float* b2 = (const float*)d_in[12];
  float* outp = (float*)d_out;

  size_t off = 0;
  auto take = [&](size_t n) {
    char* p = (char*)d_ws + off;
    off += (n + 255) & ~(size_t)255;
    return p;
  };
  unsigned short* h1 = (unsigned short*)take((size_t)NTOK * H * 2);       // also h2
  unsigned short* qkvb = (unsigned short*)take((size_t)NTOK * 3 * H * 2); // qkv; later mid
  unsigned short* attn = (unsigned short*)take((size_t)NTOK * H * 2);
  float* x1 = (float*)take((size_t)NTOK * H * 4);
  unsigned short* qkvwt = (unsigned short*)take((size_t)3 * H * H * 2);
  unsigned short* outwt = (unsigned short*)take((size_t)H * H * 2);
  unsigned short* w1t = (unsigned short*)take((size_t)H * IDIM * 2);
  unsigned short* w2t = (unsigned short*)take((size_t)H * IDIM * 2);
  float* ppart = (float*)take((size_t)2 * NTOK * H * 4);  // 64MB MLP2 partials
  bool use_sk = off <= ws_size;
  unsigned short* h2 = h1;
  unsigned short* mid = qkvb;                // [NTOK][IDIM] aliases qkv+attn exactly
  unsigned short* vt = (unsigned short*)x1;  // vt dead before proj writes x1

  dim3 tb(32, 8);
  transpose_cast_all<<<dim3(12288), tb, 0, stream>>>(qkv_w, qkvwt, out_w, outwt,
                                                     w1, w1t, w2, w2t);

  layernorm_kernel<<<NTOK, 256, 0, stream>>>(x, ln1_g, ln1_b, h1);
  gemm256_kernel<0><<<dim3(3 * H / 256, NTOK / 256), 512, 0, stream>>>(
      h1, qkvwt, qkv_b, qkvb, vt, NTOK, 3 * H, H);
  flash_attn_kernel<<<dim3(SEQ / 256 * BATCH * NHEAD), 512, 0, stream>>>(qkvb, vt, attn);
  gemm_bt_kernel<2><<<dim3(H / 128, NTOK / 128), 256, 0, stream>>>(
      attn, outwt, out_b, x, x1, nullptr, NTOK, H, H);
  layernorm_kernel<<<NTOK, 256, 0, stream>>>(x1, ln2_g, ln2_b, h2);
  gemm256_kernel<1><<<dim3(IDIM / 256, NTOK / 256), 512, 0, stream>>>(
      h2, w1t, b1, mid, nullptr, NTOK, IDIM, H);
  if (use_sk) {
    gemm256_sk_kernel<<<dim3(256), 512, 0, stream>>>(mid, w2t, ppart, NTOK, H, IDIM, IDIM / 2);
    mlp2_combine_kernel<<<dim3(NTOK), 256, 0, stream>>>(ppart, b2, x1, outp);
  } else {
    gemm_bt_kernel<2><<<dim3(H / 128, NTOK / 128), 256, 0, stream>>>(
        mid, w2t, b2, x1, outp, nullptr, NTOK, H, IDIM);
  }
}